// Round 14
// baseline (1135.982 us; speedup 1.0000x reference)
//
#include <hip/hip_runtime.h>
#include <hip/hip_bf16.h>
#include <math.h>

constexpr int Bc   = 4;
constexpr int Nc   = 200;
constexpr int Cc   = 64;
constexpr int Mc   = 600;    // 3*N
constexpr int ATTc = 128;
constexpr int OUTFc = 128;
constexpr int PREDc = 12;
constexpr int MAXBW = 40;
constexpr int MPAD  = 640;   // padded V^T leading dim

typedef short short8 __attribute__((ext_vector_type(8)));
typedef float f32x4  __attribute__((ext_vector_type(4)));

static __device__ __forceinline__ void bsplit(float v, short& h, short& l) {
    __hip_bfloat16 hb = __float2bfloat16(v);
    float hf = __bfloat162float(hb);
    __hip_bfloat16 lb = __float2bfloat16(v - hf);
    h = *(short*)&hb; l = *(short*)&lb;
}

// ---------------- embed + sliding window ----------------
__global__ __launch_bounds__(256)
void embed_window_k(const float* __restrict__ src, const float* __restrict__ temb,
                    const float* __restrict__ semb, float* __restrict__ dst,
                    int Tin, int nw, long total)
{
    long idx = (long)blockIdx.x * 256 + threadIdx.x;
    if (idx >= total) return;
    int c = (int)(idx & 63);
    long r = idx >> 6;
    int n = (int)(r % Nc); r /= Nc;
    int j = (int)(r % 3);  r /= 3;
    int w = (int)(r % nw);
    int b = (int)(r / nw);
    int t = w + j;
    dst[idx] = src[(((long)b * Tin + t) * Nc + n) * Cc + c]
             + temb[t * Cc + c] + semb[n * Cc + c];
}

// ------- fused node-mean + NA/NB projection -> bf16 hi/lo outputs ---------
__global__ __launch_bounds__(256)
void mean_nab_k(const float* __restrict__ cur, const float* __restrict__ Wa,
                const float* __restrict__ Wb,
                ushort* __restrict__ NAH, ushort* __restrict__ NAL,
                ushort* __restrict__ NBH, ushort* __restrict__ NBL, int BW)
{
    __shared__ float Ns[64][17];   // [k][row]
    __shared__ float Ws[64][132];  // [k][ Wa | Wb ]
    const int m0 = blockIdx.x * 16;
    const int t = threadIdx.x;
    for (int e = t; e < 1024; e += 256) {
        int r = e >> 4, c4 = (e & 15) << 2;
        *(float4*)&Ws[r][c4]      = *(const float4*)&Wa[r * 64 + c4];
        *(float4*)&Ws[r][64 + c4] = *(const float4*)&Wb[r * 64 + c4];
    }
    {
        int row = t >> 4, c4 = (t & 15) << 2;
        int gm = m0 + row;
        float4 sv = make_float4(0.f, 0.f, 0.f, 0.f);
        if (gm < Mc) {
            for (int bw = 0; bw < BW; bw++) {
                const float4 v = *(const float4*)&cur[((long)bw * Mc + gm) * Cc + c4];
                sv.x += v.x; sv.y += v.y; sv.z += v.z; sv.w += v.w;
            }
        }
        const float inv = 1.f / BW;
        Ns[c4 + 0][row] = sv.x * inv; Ns[c4 + 1][row] = sv.y * inv;
        Ns[c4 + 2][row] = sv.z * inv; Ns[c4 + 3][row] = sv.w * inv;
    }
    __syncthreads();
    const int row = t >> 4, c8 = (t & 15) * 8;
    float acc[8] = {};
    for (int k = 0; k < 64; k++) {
        float a = Ns[k][row];
        float b[8];
        *(float4*)&b[0] = *(const float4*)&Ws[k][c8];
        *(float4*)&b[4] = *(const float4*)&Ws[k][c8 + 4];
#pragma unroll
        for (int j = 0; j < 8; j++) acc[j] += a * b[j];
    }
    int gm = m0 + row;
    if (gm < Mc) {
#pragma unroll
        for (int j = 0; j < 8; j++) {
            int col = c8 + j;
            short h, l;
            bsplit(acc[j], h, l);
            if (col < 64) { NAH[gm * 64 + col] = (ushort)h; NAL[gm * 64 + col] = (ushort)l; }
            else { NBH[gm * 64 + col - 64] = (ushort)h; NBL[gm * 64 + col - 64] = (ushort)l; }
        }
    }
}

// ---- adj = sigmoid( (NA NB^T) / 8 ): split-bf16 MFMA, 128-tiles, grid 5x5 -
__global__ __launch_bounds__(256)
void adjmm_k(const ushort* __restrict__ Ah, const ushort* __restrict__ Al,
             const ushort* __restrict__ Bh, const ushort* __restrict__ Bl,
             float* __restrict__ ADJ)
{
    __shared__ __align__(16) ushort As[2][128][40];
    __shared__ __align__(16) ushort Bs[2][128][40];
    const int m0 = blockIdx.y * 128, n0 = blockIdx.x * 128;
    const int t = threadIdx.x;
    const int lane = t & 63, w = t >> 6;
    const int wm = (w >> 1) * 64, wn = (w & 1) * 64;
    const int lm = lane & 15, lq = lane >> 4;

    f32x4 acc[4][4];
#pragma unroll
    for (int i = 0; i < 4; i++)
#pragma unroll
        for (int j = 0; j < 4; j++)
#pragma unroll
            for (int r = 0; r < 4; r++) acc[i][j][r] = 0.f;

    for (int k0 = 0; k0 < 64; k0 += 32) {
        __syncthreads();
#pragma unroll
        for (int p = 0; p < 2; p++) {
            int e = t + p * 256;
            int row = e >> 2, ks = (e & 3) << 3;
            {
                int gm = m0 + row;
                short8 vh, vl;
#pragma unroll
                for (int q = 0; q < 8; q++) { vh[q] = 0; vl[q] = 0; }
                if (gm < Mc) {
                    vh = *(const short8*)(Ah + (long)gm * 64 + k0 + ks);
                    vl = *(const short8*)(Al + (long)gm * 64 + k0 + ks);
                }
                *(short8*)&As[0][row][ks] = vh;
                *(short8*)&As[1][row][ks] = vl;
            }
            {
                int gn = n0 + row;
                short8 vh, vl;
#pragma unroll
                for (int q = 0; q < 8; q++) { vh[q] = 0; vl[q] = 0; }
                if (gn < Mc) {
                    vh = *(const short8*)(Bh + (long)gn * 64 + k0 + ks);
                    vl = *(const short8*)(Bl + (long)gn * 64 + k0 + ks);
                }
                *(short8*)&Bs[0][row][ks] = vh;
                *(short8*)&Bs[1][row][ks] = vl;
            }
        }
        __syncthreads();

        short8 af[4][2], bf[4][2];
#pragma unroll
        for (int i = 0; i < 4; i++) {
            af[i][0] = *(const short8*)&As[0][wm + i * 16 + lm][lq * 8];
            af[i][1] = *(const short8*)&As[1][wm + i * 16 + lm][lq * 8];
        }
#pragma unroll
        for (int j = 0; j < 4; j++) {
            bf[j][0] = *(const short8*)&Bs[0][wn + j * 16 + lm][lq * 8];
            bf[j][1] = *(const short8*)&Bs[1][wn + j * 16 + lm][lq * 8];
        }
#pragma unroll
        for (int i = 0; i < 4; i++)
#pragma unroll
            for (int j = 0; j < 4; j++) {
                acc[i][j] = __builtin_amdgcn_mfma_f32_16x16x32_bf16(af[i][0], bf[j][0], acc[i][j], 0, 0, 0);
                acc[i][j] = __builtin_amdgcn_mfma_f32_16x16x32_bf16(af[i][0], bf[j][1], acc[i][j], 0, 0, 0);
                acc[i][j] = __builtin_amdgcn_mfma_f32_16x16x32_bf16(af[i][1], bf[j][0], acc[i][j], 0, 0, 0);
            }
    }
#pragma unroll
    for (int i = 0; i < 4; i++) {
        int gmb = m0 + wm + i * 16 + lq * 4;
#pragma unroll
        for (int j = 0; j < 4; j++) {
            int gn = n0 + wn + j * 16 + lm;
            if (gn >= Mc) continue;
#pragma unroll
            for (int r = 0; r < 4; r++) {
                int gm = gmb + r;
                if (gm < Mc)
                    ADJ[(long)gm * Mc + gn] = 1.f / (1.f + __expf(-acc[i][j][r] * 0.125f));
            }
        }
    }
}

// ---------------- QKV GEMM -> hi/lo bf16 buffers, XCD-swizzled -------------
__global__ __launch_bounds__(256)
void qkv_split_k(const float* __restrict__ CURp, const float* __restrict__ Wqkv,
                 const float* __restrict__ bias,
                 ushort* __restrict__ QH, ushort* __restrict__ QL,
                 ushort* __restrict__ KH, ushort* __restrict__ KL,
                 ushort* __restrict__ VTH, ushort* __restrict__ VTL)
{
    __shared__ float As[16][132];
    __shared__ float Bs[16][132];
    const int bid = blockIdx.x;
    const int xcd = bid & 7, slot = bid >> 3;
    const int z = (slot / 15) * 8 + xcd;
    const int r15 = slot % 15;
    const int which = r15 % 3;             // 0=q 1=k 2=v
    const int m0 = (r15 / 3) * 128;
    const float* A = CURp + (long)z * Mc * Cc;
    const int n0 = which * 128;
    const int t = threadIdx.x;
    const int tx = t & 15, ty = t >> 4;
    float acc[8][8] = {};

    for (int k0 = 0; k0 < 64; k0 += 16) {
#pragma unroll
        for (int pass = 0; pass < 2; pass++) {
            int e = t + pass * 256;
            int rr = e >> 2, kb = (e & 3) << 2;
            int gm = m0 + rr;
            float4 v = make_float4(0.f, 0.f, 0.f, 0.f);
            if (gm < Mc) v = *(const float4*)(A + (long)gm * 64 + k0 + kb);
            As[kb + 0][rr] = v.x; As[kb + 1][rr] = v.y;
            As[kb + 2][rr] = v.z; As[kb + 3][rr] = v.w;
        }
#pragma unroll
        for (int pass = 0; pass < 2; pass++) {
            int e = t + pass * 256;
            int kk = e >> 5, n4 = (e & 31) << 2;
            float4 v = *(const float4*)(Wqkv + (long)(k0 + kk) * 384 + n0 + n4);
            *(float4*)&Bs[kk][n4] = v;
        }
        __syncthreads();
#pragma unroll
        for (int kk = 0; kk < 16; kk++) {
            float a[8], b[8];
            *(float4*)&a[0] = *(const float4*)&As[kk][ty * 8];
            *(float4*)&a[4] = *(const float4*)&As[kk][ty * 8 + 4];
            *(float4*)&b[0] = *(const float4*)&Bs[kk][tx * 8];
            *(float4*)&b[4] = *(const float4*)&Bs[kk][tx * 8 + 4];
#pragma unroll
            for (int i = 0; i < 8; i++)
#pragma unroll
                for (int j = 0; j < 8; j++) acc[i][j] += a[i] * b[j];
        }
        __syncthreads();
    }

    if (which == 2) {
        if (m0 + ty * 8 < Mc) {
            ushort* vh = VTH + (long)z * ATTc * MPAD;
            ushort* vl = VTL + (long)z * ATTc * MPAD;
#pragma unroll
            for (int j = 0; j < 8; j++) {
                int col = tx * 8 + j;
                short8 h8, l8;
#pragma unroll
                for (int i = 0; i < 8; i++) {
                    float v = fmaxf(acc[i][j] + bias[n0 + col], 0.f);
                    short hs, ls;
                    bsplit(v, hs, ls);
                    h8[i] = hs; l8[i] = ls;
                }
                *(short8*)(vh + (long)col * MPAD + m0 + ty * 8) = h8;
                *(short8*)(vl + (long)col * MPAD + m0 + ty * 8) = l8;
            }
        }
    } else {
        ushort* dh = (which == 0 ? QH : KH) + (long)z * Mc * ATTc;
        ushort* dl = (which == 0 ? QL : KL) + (long)z * Mc * ATTc;
#pragma unroll
        for (int i = 0; i < 8; i++) {
            int row = m0 + ty * 8 + i;
            if (row >= Mc) continue;
            short8 h8, l8;
#pragma unroll
            for (int j = 0; j < 8; j++) {
                float v = acc[i][j] + bias[n0 + tx * 8 + j];
                short hs, ls;
                bsplit(v, hs, ls);
                h8[j] = hs; l8[j] = ls;
            }
            *(short8*)(dh + (long)row * ATTc + tx * 8) = h8;
            *(short8*)(dl + (long)row * ATTc + tx * 8) = l8;
        }
    }
}

// ---- fused attention v3: frag-major K staging (conflict-free LDS), V ------
// frags direct from global (vmem pipe), P wave-private. Grid BW*10 XCD-
// swizzled, 64 q-rows/block, 4 waves x 16 rows. No-max softmax (exact).
__global__ __launch_bounds__(256)
void attn_k(const ushort* __restrict__ QH, const ushort* __restrict__ QL,
            const ushort* __restrict__ KH, const ushort* __restrict__ KL,
            const ushort* __restrict__ VTH, const ushort* __restrict__ VTL,
            const float* __restrict__ adj, uint* __restrict__ OB, float scale)
{
    // frag-major K stage: slot s = j*128 + kk*64 + lane holds 8 ushorts of
    // K[key=kc+j*16+(lane&15)][att = g*64 + kk*32 + (lane>>4)*8 ..+7]
    __shared__ __align__(16) ushort KSh[8192];        // 16 KB
    __shared__ __align__(16) ushort KSl[8192];        // 16 KB
    __shared__ __align__(16) ushort PH[4][16][152];   // wave-private P hi
    __shared__ __align__(16) ushort PL[4][16][152];   //                lo
    const int bid = blockIdx.x;
    const int xcd = bid & 7, slot = bid >> 3;
    const int z = (slot / 10) * 8 + xcd;
    const int m0 = (slot % 10) * 64;
    const int t = threadIdx.x;
    const int lane = t & 63, w = t >> 6;
    const int lm = lane & 15, lq = lane >> 4;
    const int qrow0 = m0 + w * 16;

    const ushort* Qhz = QH + (long)z * Mc * ATTc;
    const ushort* Qlz = QL + (long)z * Mc * ATTc;
    const ushort* Khz = KH + (long)z * Mc * ATTc;
    const ushort* Klz = KL + (long)z * Mc * ATTc;
    const ushort* Vhz = VTH + (long)z * ATTc * MPAD;
    const ushort* Vlz = VTL + (long)z * ATTc * MPAD;

    short8 qh[4], ql[4];
    {
        int qr = qrow0 + lm;
        if (qr < Mc) {
            const ushort* qp = Qhz + (long)qr * ATTc;
            const ushort* qp2 = Qlz + (long)qr * ATTc;
#pragma unroll
            for (int ks = 0; ks < 4; ks++) {
                qh[ks] = *(const short8*)(qp + ks * 32 + lq * 8);
                ql[ks] = *(const short8*)(qp2 + ks * 32 + lq * 8);
            }
        } else {
#pragma unroll
            for (int ks = 0; ks < 4; ks++)
#pragma unroll
                for (int q = 0; q < 8; q++) { qh[ks][q] = 0; ql[ks][q] = 0; }
        }
    }

    f32x4 oacc[8];
#pragma unroll
    for (int j = 0; j < 8; j++)
#pragma unroll
        for (int r = 0; r < 4; r++) oacc[j][r] = 0.f;
    float Er[4] = {}, Sr[4] = {};

    for (int kc = 0; kc < 640; kc += 128) {       // 5 key chunks
        f32x4 sacc[8];
#pragma unroll
        for (int j = 0; j < 8; j++)
#pragma unroll
            for (int r = 0; r < 4; r++) sacc[j][r] = 0.f;

        // ---- QK phase: 2 frag-major staging rounds of 64 att ----
#pragma unroll
        for (int g = 0; g < 2; g++) {
            __syncthreads();
#pragma unroll
            for (int p = 0; p < 4; p++) {
                int s = t + p * 256;              // 0..1023
                int slm = s & 15, slq = (s >> 4) & 3;
                int skk = (s >> 6) & 1, sj = s >> 7;
                int key = kc + sj * 16 + slm;
                int att = g * 64 + skk * 32 + slq * 8;
                short8 vh, vl;
#pragma unroll
                for (int q = 0; q < 8; q++) { vh[q] = 0; vl[q] = 0; }
                if (key < Mc) {
                    vh = *(const short8*)(Khz + (long)key * ATTc + att);
                    vl = *(const short8*)(Klz + (long)key * ATTc + att);
                }
                *(short8*)&KSh[s * 8] = vh;       // lane-sequential: conflict-free
                *(short8*)&KSl[s * 8] = vl;
            }
            __syncthreads();
#pragma unroll
            for (int kk = 0; kk < 2; kk++) {
                int ks = g * 2 + kk;
#pragma unroll
                for (int j = 0; j < 8; j++) {
                    int base = (j * 128 + kk * 64 + lane) * 8;   // sequential
                    short8 bh = *(const short8*)&KSh[base];
                    short8 bl = *(const short8*)&KSl[base];
                    sacc[j] = __builtin_amdgcn_mfma_f32_16x16x32_bf16(qh[ks], bh, sacc[j], 0, 0, 0);
                    sacc[j] = __builtin_amdgcn_mfma_f32_16x16x32_bf16(qh[ks], bl, sacc[j], 0, 0, 0);
                    sacc[j] = __builtin_amdgcn_mfma_f32_16x16x32_bf16(ql[ks], bh, sacc[j], 0, 0, 0);
                }
            }
        }

        // ---- epilogue: P = exp(s*scale)*adj -> wave-private LDS ----
#pragma unroll
        for (int j = 0; j < 8; j++) {
            int col = kc + j * 16 + lm;
            bool cok = col < Mc;
#pragma unroll
            for (int r = 0; r < 4; r++) {
                int row = qrow0 + lq * 4 + r;
                float e = cok ? __expf(sacc[j][r] * scale) : 0.f;
                float a = (cok && row < Mc) ? adj[(long)row * Mc + col] : 0.f;
                float p = e * a;
                Er[r] += e; Sr[r] += p;
                short hs, ls;
                bsplit(p, hs, ls);
                PH[w][lq * 4 + r][j * 16 + lm] = (ushort)hs;
                PL[w][lq * 4 + r][j * 16 + lm] = (ushort)ls;
            }
        }

        // ---- PV phase: P from LDS, V frags direct from global ----
#pragma unroll
        for (int kk2 = 0; kk2 < 4; kk2++) {
            short8 ph = *(const short8*)&PH[w][lm][kk2 * 32 + lq * 8];
            short8 pl = *(const short8*)&PL[w][lm][kk2 * 32 + lq * 8];
#pragma unroll
            for (int at = 0; at < 8; at++) {
                const long vo = (long)(at * 16 + lm) * MPAD + kc + kk2 * 32 + lq * 8;
                short8 vh = *(const short8*)(Vhz + vo);   // pad keys: P=0 masks
                short8 vl = *(const short8*)(Vlz + vo);
                oacc[at] = __builtin_amdgcn_mfma_f32_16x16x32_bf16(ph, vh, oacc[at], 0, 0, 0);
                oacc[at] = __builtin_amdgcn_mfma_f32_16x16x32_bf16(ph, vl, oacc[at], 0, 0, 0);
                oacc[at] = __builtin_amdgcn_mfma_f32_16x16x32_bf16(pl, vh, oacc[at], 0, 0, 0);
            }
        }
    }

    // ---- row sums, then packed bf16 hi/lo store ----
#pragma unroll
    for (int mk = 1; mk <= 8; mk <<= 1)
#pragma unroll
        for (int r = 0; r < 4; r++) {
            Er[r] += __shfl_xor(Er[r], mk, 64);
            Sr[r] += __shfl_xor(Sr[r], mk, 64);
        }
    float inv[4];
#pragma unroll
    for (int r = 0; r < 4; r++) inv[r] = 1.f / (Sr[r] + 1e-8f * Er[r]);
    uint* Oz = OB + (long)z * Mc * ATTc;
#pragma unroll
    for (int j = 0; j < 8; j++)
#pragma unroll
        for (int r = 0; r < 4; r++) {
            int row = qrow0 + lq * 4 + r;
            if (row < Mc) {
                float v = oacc[j][r] * inv[r];
                short hs, ls;
                bsplit(v, hs, ls);
                Oz[(long)row * ATTc + j * 16 + lm] =
                    ((uint)(ushort)ls << 16) | (uint)(ushort)hs;
            }
        }
}

// ---------------- Wlin^T prep: transpose + bf16 hi/lo split ----------------
__global__ __launch_bounds__(256)
void wlin_prep_k(const float* __restrict__ Wlin,
                 ushort* __restrict__ WTH, ushort* __restrict__ WTL)
{
    int i = blockIdx.x * 256 + threadIdx.x;
    if (i >= 64 * 128) return;
    int c = i >> 7, a = i & 127;
    short h, l;
    bsplit(Wlin[a * 64 + c], h, l);
    WTH[c * 128 + a] = (ushort)h;
    WTL[c * 128 + a] = (ushort)l;
}

// ---- Wlin GEMM: CUR = unpack(OB) @ Wlin + blin (split-bf16 MFMA) ----------
__global__ __launch_bounds__(256)
void wlin_k(const uint* __restrict__ OB, const ushort* __restrict__ WTH,
            const ushort* __restrict__ WTL, const float* __restrict__ blin,
            float* __restrict__ CUR, int Mtot)
{
    __shared__ __align__(16) ushort As[2][128][40];
    __shared__ __align__(16) ushort Bs[2][64][136];
    const int m0 = blockIdx.x * 128;
    const int t = threadIdx.x;
    const int lane = t & 63, w = t >> 6;
    const int wm = (w >> 1) * 64, wn = (w & 1) * 32;
    const int lm = lane & 15, lq = lane >> 4;

#pragma unroll
    for (int p = 0; p < 4; p++) {
        int e = t + p * 256;
        int row = e >> 4, seg = (e & 15) << 3;
        *(short8*)&Bs[0][row][seg] = *(const short8*)(WTH + row * 128 + seg);
        *(short8*)&Bs[1][row][seg] = *(const short8*)(WTL + row * 128 + seg);
    }

    f32x4 acc[4][2];
#pragma unroll
    for (int i = 0; i < 4; i++)
#pragma unroll
        for (int j = 0; j < 2; j++)
#pragma unroll
            for (int r = 0; r < 4; r++) acc[i][j][r] = 0.f;

    for (int k0 = 0; k0 < 128; k0 += 32) {
        __syncthreads();
#pragma unroll
        for (int p = 0; p < 2; p++) {
            int e = t + p * 256;
            int row = e >> 2, seg = (e & 3) << 3;
            int gm = m0 + row;
            short8 vh, vl;
#pragma unroll
            for (int q = 0; q < 8; q++) { vh[q] = 0; vl[q] = 0; }
            if (gm < Mtot) {
                const uint4 u0 = *(const uint4*)(OB + (long)gm * 128 + k0 + seg);
                const uint4 u1 = *(const uint4*)(OB + (long)gm * 128 + k0 + seg + 4);
#pragma unroll
                for (int q = 0; q < 4; q++) {
                    uint u = ((const uint*)&u0)[q];
                    vh[q] = (short)(u & 0xffff); vl[q] = (short)(u >> 16);
                }
#pragma unroll
                for (int q = 0; q < 4; q++) {
                    uint u = ((const uint*)&u1)[q];
                    vh[4 + q] = (short)(u & 0xffff); vl[4 + q] = (short)(u >> 16);
                }
            }
            *(short8*)&As[0][row][seg] = vh;
            *(short8*)&As[1][row][seg] = vl;
        }
        __syncthreads();

        short8 af[4][2], bf[2][2];
#pragma unroll
        for (int i = 0; i < 4; i++) {
            af[i][0] = *(const short8*)&As[0][wm + i * 16 + lm][lq * 8];
            af[i][1] = *(const short8*)&As[1][wm + i * 16 + lm][lq * 8];
        }
#pragma unroll
        for (int j = 0; j < 2; j++) {
            bf[j][0] = *(const short8*)&Bs[0][wn + j * 16 + lm][k0 + lq * 8];
            bf[j][1] = *(const short8*)&Bs[1][wn + j * 16 + lm][k0 + lq * 8];
        }
#pragma unroll
        for (int i = 0; i < 4; i++)
#pragma unroll
            for (int j = 0; j < 2; j++) {
                acc[i][j] = __builtin_amdgcn_mfma_f32_16x16x32_bf16(af[i][0], bf[j][0], acc[i][j], 0, 0, 0);
                acc[i][j] = __builtin_amdgcn_mfma_f32_16x16x32_bf16(af[i][0], bf[j][1], acc[i][j], 0, 0, 0);
                acc[i][j] = __builtin_amdgcn_mfma_f32_16x16x32_bf16(af[i][1], bf[j][0], acc[i][j], 0, 0, 0);
            }
    }
#pragma unroll
    for (int i = 0; i < 4; i++) {
        int gmb = m0 + wm + i * 16 + lq * 4;
#pragma unroll
        for (int j = 0; j < 2; j++) {
            int col = wn + j * 16 + lm;
            float b = blin[col];
#pragma unroll
            for (int r = 0; r < 4; r++) {
                int gm = gmb + r;
                if (gm < Mtot) CUR[(long)gm * 64 + col] = acc[i][j][r] + b;
            }
        }
    }
}

// ---------------- running max of middle-window slice [2N:3N] ---------------
__global__ __launch_bounds__(256)
void cand_update_k(const float* __restrict__ cur, float* __restrict__ cand,
                   int bw0, long total, int first)
{
    long idx = (long)blockIdx.x * 256 + threadIdx.x;
    if (idx >= total) return;
    int c = (int)(idx & 63);
    long r = idx >> 6;
    int n = (int)(r % Nc);
    int i = (int)(r / Nc);
    long bw = bw0 + i;
    float v = cur[((bw * Mc) + 2 * Nc + n) * Cc + c];
    long o = ((bw * Nc) + n) * Cc + c;
    cand[o] = first ? v : fmaxf(cand[o], v);
}

// ---------------- output layer ----------------
__global__ __launch_bounds__(128)
void output_k(const float* __restrict__ h2, const float* __restrict__ Wo,
              const float* __restrict__ bo, float* __restrict__ out)
{
    __shared__ float ds[512];
    int row = blockIdx.x;
    int b = row / Nc, n = row % Nc;
    int t = threadIdx.x;
    for (int e = t; e < 512; e += 128) {
        int tt = e >> 6, c = e & 63;
        ds[e] = h2[(((long)b * 8 + tt) * Nc + n) * Cc + c];
    }
    __syncthreads();
    float acc = bo[t];
    for (int e = 0; e < 512; e++) acc += ds[e] * Wo[e * OUTFc + t];
    acc = fmaxf(acc, 0.f);
    for (int p = 0; p < PREDc; p++)
        out[(((long)b * PREDc + p) * Nc + n) * (long)OUTFc + t] = acc;
}

extern "C" void kernel_launch(void* const* d_in, const int* in_sizes, int n_in,
                              void* d_out, int out_size, void* d_ws, size_t ws_size,
                              hipStream_t stream)
{
    (void)in_sizes; (void)n_in; (void)out_size; (void)ws_size;
    const float* x     = (const float*)d_in[0];
    const float* Wqkv  = (const float*)d_in[4];
    const float* bqkv  = (const float*)d_in[5];
    const float* Wlin  = (const float*)d_in[6];
    const float* blin  = (const float*)d_in[7];
    const float* Wa    = (const float*)d_in[8];
    const float* Wb    = (const float*)d_in[9];
    const float* temb0 = (const float*)d_in[13];
    const float* temb1 = (const float*)d_in[14];
    const float* semb  = (const float*)d_in[15];
    const float* Wo    = (const float*)d_in[16];
    const float* bo    = (const float*)d_in[17];
    float* out = (float*)d_out;

    // ---- workspace (float offsets), ~60 MB ----
    float* ws   = (float*)d_ws;
    float* CUR  = ws;                                  // 1,536,000
    float* ADJ  = CUR + (long)MAXBW * Mc * Cc;         // 360,000
    float* CAND = ADJ + (long)Mc * Mc;                 // 512,000
    uint*  OB   = (uint*)(CAND + (long)MAXBW * Nc * Cc); // 3,072,000 u32
    float* QHf  = (float*)(OB + (long)MAXBW * Mc * ATTc);
    const long QSZ = (long)MAXBW * Mc * ATTc / 2;      // in floats
    float* QLf  = QHf + QSZ;
    float* KHf  = QLf + QSZ;
    float* KLf  = KHf + QSZ;
    float* VTHf = KLf + QSZ;
    float* VTLf = VTHf + (long)MAXBW * ATTc * MPAD / 2;
    ushort* NAH = (ushort*)(VTLf + (long)MAXBW * ATTc * MPAD / 2);
    ushort* NAL = NAH + Mc * Cc;
    ushort* NBH = NAL + Mc * Cc;
    ushort* NBL = NBH + Mc * Cc;
    ushort* WTH = NBL + Mc * Cc;                       // 64*128 each
    ushort* WTL = WTH + 64 * 128;

    ushort* QH  = (ushort*)QHf;
    ushort* QL  = (ushort*)QLf;
    ushort* KH  = (ushort*)KHf;
    ushort* KL  = (ushort*)KLf;
    ushort* VTH = (ushort*)VTHf;
    ushort* VTL = (ushort*)VTLf;

    const float inv_sqrt_att = 0.08838834764831845f;   // 1/sqrt(128)

    // Wlin^T hi/lo (weights constant across iterations)
    wlin_prep_k<<<dim3(32), dim3(256), 0, stream>>>(Wlin, WTH, WTL);

    for (int layer = 0; layer < 2; layer++) {
        int Tin = layer ? 10 : 12;
        int nw  = Tin - 2;
        int BW  = Bc * nw;                             // 40 then 32
        int Mtot = BW * Mc;
        const float* src  = layer ? CAND : x;
        const float* temb = layer ? temb1 : temb0;

        long etotal = (long)BW * Mc * Cc;
        embed_window_k<<<dim3((unsigned)((etotal + 255) / 256)), dim3(256), 0, stream>>>(
            src, temb, semb, CUR, Tin, nw, etotal);

        for (int it = 0; it < 3; it++) {
            // adjacency: mean -> NA/NB (bf16 split) -> sigmoid MFMA
            mean_nab_k<<<dim3(38), dim3(256), 0, stream>>>(
                CUR, Wa, Wb, NAH, NAL, NBH, NBL, BW);
            adjmm_k<<<dim3(5, 5), dim3(256), 0, stream>>>(
                NAH, NAL, NBH, NBL, ADJ);

            // QKV projection + hi/lo split (XCD-swizzled)
            qkv_split_k<<<dim3(BW * 15), dim3(256), 0, stream>>>(
                CUR, Wqkv, bqkv, QH, QL, KH, KL, VTH, VTL);

            // fused attention v3 (frag-major K stage, V direct)
            attn_k<<<dim3(BW * 10), dim3(256), 0, stream>>>(
                QH, QL, KH, KL, VTH, VTL, ADJ, OB, inv_sqrt_att);

            // cur = O @ Wlin + blin (split-bf16 MFMA)
            wlin_k<<<dim3((Mtot + 127) / 128), dim3(256), 0, stream>>>(
                OB, WTH, WTL, blin, CUR, Mtot);

            // running max of middle window
            long mtot = (long)BW * Nc * Cc;
            cand_update_k<<<dim3((unsigned)((mtot + 255) / 256)), dim3(256), 0, stream>>>(
                CUR, CAND, 0, mtot, it == 0 ? 1 : 0);
        }
    }
    output_k<<<dim3(Bc * Nc), dim3(128), 0, stream>>>(CAND, Wo, bo, out);
}

// Round 15
// 916.527 us; speedup vs baseline: 1.2394x; 1.2394x over previous
//
#include <hip/hip_runtime.h>
#include <hip/hip_bf16.h>
#include <math.h>

constexpr int Bc   = 4;
constexpr int Nc   = 200;
constexpr int Cc   = 64;
constexpr int Mc   = 600;    // 3*N
constexpr int ATTc = 128;
constexpr int OUTFc = 128;
constexpr int PREDc = 12;
constexpr int MAXBW = 40;
constexpr int MPAD  = 640;   // padded V^T leading dim

typedef short short8 __attribute__((ext_vector_type(8)));
typedef float f32x4  __attribute__((ext_vector_type(4)));

static __device__ __forceinline__ void bsplit(float v, short& h, short& l) {
    __hip_bfloat16 hb = __float2bfloat16(v);
    float hf = __bfloat162float(hb);
    __hip_bfloat16 lb = __float2bfloat16(v - hf);
    h = *(short*)&hb; l = *(short*)&lb;
}

// ---------------- embed + sliding window ----------------
__global__ __launch_bounds__(256)
void embed_window_k(const float* __restrict__ src, const float* __restrict__ temb,
                    const float* __restrict__ semb, float* __restrict__ dst,
                    int Tin, int nw, long total)
{
    long idx = (long)blockIdx.x * 256 + threadIdx.x;
    if (idx >= total) return;
    int c = (int)(idx & 63);
    long r = idx >> 6;
    int n = (int)(r % Nc); r /= Nc;
    int j = (int)(r % 3);  r /= 3;
    int w = (int)(r % nw);
    int b = (int)(r / nw);
    int t = w + j;
    dst[idx] = src[(((long)b * Tin + t) * Nc + n) * Cc + c]
             + temb[t * Cc + c] + semb[n * Cc + c];
}

// ------- fused node-mean + NA/NB projection -> bf16 hi/lo outputs ---------
__global__ __launch_bounds__(256)
void mean_nab_k(const float* __restrict__ cur, const float* __restrict__ Wa,
                const float* __restrict__ Wb,
                ushort* __restrict__ NAH, ushort* __restrict__ NAL,
                ushort* __restrict__ NBH, ushort* __restrict__ NBL, int BW)
{
    __shared__ float Ns[64][17];   // [k][row]
    __shared__ float Ws[64][132];  // [k][ Wa | Wb ]
    const int m0 = blockIdx.x * 16;
    const int t = threadIdx.x;
    for (int e = t; e < 1024; e += 256) {
        int r = e >> 4, c4 = (e & 15) << 2;
        *(float4*)&Ws[r][c4]      = *(const float4*)&Wa[r * 64 + c4];
        *(float4*)&Ws[r][64 + c4] = *(const float4*)&Wb[r * 64 + c4];
    }
    {
        int row = t >> 4, c4 = (t & 15) << 2;
        int gm = m0 + row;
        float4 sv = make_float4(0.f, 0.f, 0.f, 0.f);
        if (gm < Mc) {
            for (int bw = 0; bw < BW; bw++) {
                const float4 v = *(const float4*)&cur[((long)bw * Mc + gm) * Cc + c4];
                sv.x += v.x; sv.y += v.y; sv.z += v.z; sv.w += v.w;
            }
        }
        const float inv = 1.f / BW;
        Ns[c4 + 0][row] = sv.x * inv; Ns[c4 + 1][row] = sv.y * inv;
        Ns[c4 + 2][row] = sv.z * inv; Ns[c4 + 3][row] = sv.w * inv;
    }
    __syncthreads();
    const int row = t >> 4, c8 = (t & 15) * 8;
    float acc[8] = {};
    for (int k = 0; k < 64; k++) {
        float a = Ns[k][row];
        float b[8];
        *(float4*)&b[0] = *(const float4*)&Ws[k][c8];
        *(float4*)&b[4] = *(const float4*)&Ws[k][c8 + 4];
#pragma unroll
        for (int j = 0; j < 8; j++) acc[j] += a * b[j];
    }
    int gm = m0 + row;
    if (gm < Mc) {
#pragma unroll
        for (int j = 0; j < 8; j++) {
            int col = c8 + j;
            short h, l;
            bsplit(acc[j], h, l);
            if (col < 64) { NAH[gm * 64 + col] = (ushort)h; NAL[gm * 64 + col] = (ushort)l; }
            else { NBH[gm * 64 + col - 64] = (ushort)h; NBL[gm * 64 + col - 64] = (ushort)l; }
        }
    }
}

// ---- adj = sigmoid( (NA NB^T) / 8 ): split-bf16 MFMA, 128-tiles, grid 5x5 -
__global__ __launch_bounds__(256)
void adjmm_k(const ushort* __restrict__ Ah, const ushort* __restrict__ Al,
             const ushort* __restrict__ Bh, const ushort* __restrict__ Bl,
             float* __restrict__ ADJ)
{
    __shared__ __align__(16) ushort As[2][128][40];
    __shared__ __align__(16) ushort Bs[2][128][40];
    const int m0 = blockIdx.y * 128, n0 = blockIdx.x * 128;
    const int t = threadIdx.x;
    const int lane = t & 63, w = t >> 6;
    const int wm = (w >> 1) * 64, wn = (w & 1) * 64;
    const int lm = lane & 15, lq = lane >> 4;

    f32x4 acc[4][4];
#pragma unroll
    for (int i = 0; i < 4; i++)
#pragma unroll
        for (int j = 0; j < 4; j++)
#pragma unroll
            for (int r = 0; r < 4; r++) acc[i][j][r] = 0.f;

    for (int k0 = 0; k0 < 64; k0 += 32) {
        __syncthreads();
#pragma unroll
        for (int p = 0; p < 2; p++) {
            int e = t + p * 256;
            int row = e >> 2, ks = (e & 3) << 3;
            {
                int gm = m0 + row;
                short8 vh, vl;
#pragma unroll
                for (int q = 0; q < 8; q++) { vh[q] = 0; vl[q] = 0; }
                if (gm < Mc) {
                    vh = *(const short8*)(Ah + (long)gm * 64 + k0 + ks);
                    vl = *(const short8*)(Al + (long)gm * 64 + k0 + ks);
                }
                *(short8*)&As[0][row][ks] = vh;
                *(short8*)&As[1][row][ks] = vl;
            }
            {
                int gn = n0 + row;
                short8 vh, vl;
#pragma unroll
                for (int q = 0; q < 8; q++) { vh[q] = 0; vl[q] = 0; }
                if (gn < Mc) {
                    vh = *(const short8*)(Bh + (long)gn * 64 + k0 + ks);
                    vl = *(const short8*)(Bl + (long)gn * 64 + k0 + ks);
                }
                *(short8*)&Bs[0][row][ks] = vh;
                *(short8*)&Bs[1][row][ks] = vl;
            }
        }
        __syncthreads();

        short8 af[4][2], bf[4][2];
#pragma unroll
        for (int i = 0; i < 4; i++) {
            af[i][0] = *(const short8*)&As[0][wm + i * 16 + lm][lq * 8];
            af[i][1] = *(const short8*)&As[1][wm + i * 16 + lm][lq * 8];
        }
#pragma unroll
        for (int j = 0; j < 4; j++) {
            bf[j][0] = *(const short8*)&Bs[0][wn + j * 16 + lm][lq * 8];
            bf[j][1] = *(const short8*)&Bs[1][wn + j * 16 + lm][lq * 8];
        }
#pragma unroll
        for (int i = 0; i < 4; i++)
#pragma unroll
            for (int j = 0; j < 4; j++) {
                acc[i][j] = __builtin_amdgcn_mfma_f32_16x16x32_bf16(af[i][0], bf[j][0], acc[i][j], 0, 0, 0);
                acc[i][j] = __builtin_amdgcn_mfma_f32_16x16x32_bf16(af[i][0], bf[j][1], acc[i][j], 0, 0, 0);
                acc[i][j] = __builtin_amdgcn_mfma_f32_16x16x32_bf16(af[i][1], bf[j][0], acc[i][j], 0, 0, 0);
            }
    }
#pragma unroll
    for (int i = 0; i < 4; i++) {
        int gmb = m0 + wm + i * 16 + lq * 4;
#pragma unroll
        for (int j = 0; j < 4; j++) {
            int gn = n0 + wn + j * 16 + lm;
            if (gn >= Mc) continue;
#pragma unroll
            for (int r = 0; r < 4; r++) {
                int gm = gmb + r;
                if (gm < Mc)
                    ADJ[(long)gm * Mc + gn] = 1.f / (1.f + __expf(-acc[i][j][r] * 0.125f));
            }
        }
    }
}

// ---------------- QKV GEMM -> hi/lo bf16 buffers, XCD-swizzled -------------
__global__ __launch_bounds__(256)
void qkv_split_k(const float* __restrict__ CURp, const float* __restrict__ Wqkv,
                 const float* __restrict__ bias,
                 ushort* __restrict__ QH, ushort* __restrict__ QL,
                 ushort* __restrict__ KH, ushort* __restrict__ KL,
                 ushort* __restrict__ VTH, ushort* __restrict__ VTL)
{
    __shared__ float As[16][132];
    __shared__ float Bs[16][132];
    const int bid = blockIdx.x;
    const int xcd = bid & 7, slot = bid >> 3;
    const int z = (slot / 15) * 8 + xcd;
    const int r15 = slot % 15;
    const int which = r15 % 3;             // 0=q 1=k 2=v
    const int m0 = (r15 / 3) * 128;
    const float* A = CURp + (long)z * Mc * Cc;
    const int n0 = which * 128;
    const int t = threadIdx.x;
    const int tx = t & 15, ty = t >> 4;
    float acc[8][8] = {};

    for (int k0 = 0; k0 < 64; k0 += 16) {
#pragma unroll
        for (int pass = 0; pass < 2; pass++) {
            int e = t + pass * 256;
            int rr = e >> 2, kb = (e & 3) << 2;
            int gm = m0 + rr;
            float4 v = make_float4(0.f, 0.f, 0.f, 0.f);
            if (gm < Mc) v = *(const float4*)(A + (long)gm * 64 + k0 + kb);
            As[kb + 0][rr] = v.x; As[kb + 1][rr] = v.y;
            As[kb + 2][rr] = v.z; As[kb + 3][rr] = v.w;
        }
#pragma unroll
        for (int pass = 0; pass < 2; pass++) {
            int e = t + pass * 256;
            int kk = e >> 5, n4 = (e & 31) << 2;
            float4 v = *(const float4*)(Wqkv + (long)(k0 + kk) * 384 + n0 + n4);
            *(float4*)&Bs[kk][n4] = v;
        }
        __syncthreads();
#pragma unroll
        for (int kk = 0; kk < 16; kk++) {
            float a[8], b[8];
            *(float4*)&a[0] = *(const float4*)&As[kk][ty * 8];
            *(float4*)&a[4] = *(const float4*)&As[kk][ty * 8 + 4];
            *(float4*)&b[0] = *(const float4*)&Bs[kk][tx * 8];
            *(float4*)&b[4] = *(const float4*)&Bs[kk][tx * 8 + 4];
#pragma unroll
            for (int i = 0; i < 8; i++)
#pragma unroll
                for (int j = 0; j < 8; j++) acc[i][j] += a[i] * b[j];
        }
        __syncthreads();
    }

    if (which == 2) {
        if (m0 + ty * 8 < Mc) {
            ushort* vh = VTH + (long)z * ATTc * MPAD;
            ushort* vl = VTL + (long)z * ATTc * MPAD;
#pragma unroll
            for (int j = 0; j < 8; j++) {
                int col = tx * 8 + j;
                short8 h8, l8;
#pragma unroll
                for (int i = 0; i < 8; i++) {
                    float v = fmaxf(acc[i][j] + bias[n0 + col], 0.f);
                    short hs, ls;
                    bsplit(v, hs, ls);
                    h8[i] = hs; l8[i] = ls;
                }
                *(short8*)(vh + (long)col * MPAD + m0 + ty * 8) = h8;
                *(short8*)(vl + (long)col * MPAD + m0 + ty * 8) = l8;
            }
        }
    } else {
        ushort* dh = (which == 0 ? QH : KH) + (long)z * Mc * ATTc;
        ushort* dl = (which == 0 ? QL : KL) + (long)z * Mc * ATTc;
#pragma unroll
        for (int i = 0; i < 8; i++) {
            int row = m0 + ty * 8 + i;
            if (row >= Mc) continue;
            short8 h8, l8;
#pragma unroll
            for (int j = 0; j < 8; j++) {
                float v = acc[i][j] + bias[n0 + tx * 8 + j];
                short hs, ls;
                bsplit(v, hs, ls);
                h8[j] = hs; l8[j] = ls;
            }
            *(short8*)(dh + (long)row * ATTc + tx * 8) = h8;
            *(short8*)(dl + (long)row * ATTc + tx * 8) = l8;
        }
    }
}

// ---- fused attention (R13 config + XOR granule swizzle on SB) -------------
// S=QK^T -> P=exp(s)*adj -> PV. Grid BW*10 XCD-swizzled, 64 q-rows/block,
// 4 waves x 16 rows, K/V cooperatively LDS-staged (coalesced global reads),
// P wave-private. SB rows are 128B (8 granules of 16B); granule g of row r
// is stored at slot g^(r&7) -> uniform bank load on frag reads, coalesced
// stores. No-max softmax (exact: shift cancels in w = e*a/(S+1e-8*E)).
__global__ __launch_bounds__(256)
void attn_k(const ushort* __restrict__ QH, const ushort* __restrict__ QL,
            const ushort* __restrict__ KH, const ushort* __restrict__ KL,
            const ushort* __restrict__ VTH, const ushort* __restrict__ VTL,
            const float* __restrict__ adj, uint* __restrict__ OB, float scale)
{
    __shared__ __align__(16) ushort SB[2][128][64];   // 32 KB, swizzled granules
    __shared__ __align__(16) ushort PH[4][16][152];   // wave-private P hi
    __shared__ __align__(16) ushort PL[4][16][152];   //                lo
    const int bid = blockIdx.x;
    const int xcd = bid & 7, slot = bid >> 3;
    const int z = (slot / 10) * 8 + xcd;
    const int m0 = (slot % 10) * 64;
    const int t = threadIdx.x;
    const int lane = t & 63, w = t >> 6;
    const int lm = lane & 15, lq = lane >> 4;
    const int qrow0 = m0 + w * 16;

    const ushort* Qhz = QH + (long)z * Mc * ATTc;
    const ushort* Qlz = QL + (long)z * Mc * ATTc;
    const ushort* Khz = KH + (long)z * Mc * ATTc;
    const ushort* Klz = KL + (long)z * Mc * ATTc;
    const ushort* Vhz = VTH + (long)z * ATTc * MPAD;
    const ushort* Vlz = VTL + (long)z * ATTc * MPAD;

    short8 qh[4], ql[4];
    {
        int qr = qrow0 + lm;
        if (qr < Mc) {
            const ushort* qp = Qhz + (long)qr * ATTc;
            const ushort* qp2 = Qlz + (long)qr * ATTc;
#pragma unroll
            for (int ks = 0; ks < 4; ks++) {
                qh[ks] = *(const short8*)(qp + ks * 32 + lq * 8);
                ql[ks] = *(const short8*)(qp2 + ks * 32 + lq * 8);
            }
        } else {
#pragma unroll
            for (int ks = 0; ks < 4; ks++)
#pragma unroll
                for (int q = 0; q < 8; q++) { qh[ks][q] = 0; ql[ks][q] = 0; }
        }
    }

    f32x4 oacc[8];
#pragma unroll
    for (int j = 0; j < 8; j++)
#pragma unroll
        for (int r = 0; r < 4; r++) oacc[j][r] = 0.f;
    float Er[4] = {}, Sr[4] = {};

    for (int kc = 0; kc < 640; kc += 128) {       // 5 key chunks
        f32x4 sacc[8];
#pragma unroll
        for (int j = 0; j < 8; j++)
#pragma unroll
            for (int r = 0; r < 4; r++) sacc[j][r] = 0.f;

        // ---- QK phase: 2 staging rounds of 64 att (coalesced + swizzled) --
#pragma unroll
        for (int g = 0; g < 2; g++) {
            __syncthreads();
#pragma unroll
            for (int p = 0; p < 4; p++) {
                int e = t + p * 256;              // 0..1023
                int row = e >> 3, gidx = e & 7;
                int key = kc + row;
                short8 vh, vl;
#pragma unroll
                for (int q = 0; q < 8; q++) { vh[q] = 0; vl[q] = 0; }
                if (key < Mc) {
                    vh = *(const short8*)(Khz + (long)key * ATTc + g * 64 + gidx * 8);
                    vl = *(const short8*)(Klz + (long)key * ATTc + g * 64 + gidx * 8);
                }
                int sw = (gidx ^ (row & 7)) * 8;
                *(short8*)&SB[0][row][sw] = vh;
                *(short8*)&SB[1][row][sw] = vl;
            }
            __syncthreads();
#pragma unroll
            for (int kk = 0; kk < 2; kk++) {
                int ks = g * 2 + kk;
#pragma unroll
                for (int j = 0; j < 8; j++) {
                    int row = j * 16 + lm;
                    int sw = ((kk * 4 + lq) ^ (lm & 7)) * 8;
                    short8 bh = *(const short8*)&SB[0][row][sw];
                    short8 bl = *(const short8*)&SB[1][row][sw];
                    sacc[j] = __builtin_amdgcn_mfma_f32_16x16x32_bf16(qh[ks], bh, sacc[j], 0, 0, 0);
                    sacc[j] = __builtin_amdgcn_mfma_f32_16x16x32_bf16(qh[ks], bl, sacc[j], 0, 0, 0);
                    sacc[j] = __builtin_amdgcn_mfma_f32_16x16x32_bf16(ql[ks], bh, sacc[j], 0, 0, 0);
                }
            }
        }

        // ---- epilogue: P = exp(s*scale)*adj -> wave-private LDS ----
#pragma unroll
        for (int j = 0; j < 8; j++) {
            int col = kc + j * 16 + lm;
            bool cok = col < Mc;
#pragma unroll
            for (int r = 0; r < 4; r++) {
                int row = qrow0 + lq * 4 + r;
                float e = cok ? __expf(sacc[j][r] * scale) : 0.f;
                float a = (cok && row < Mc) ? adj[(long)row * Mc + col] : 0.f;
                float p = e * a;
                Er[r] += e; Sr[r] += p;
                short hs, ls;
                bsplit(p, hs, ls);
                PH[w][lq * 4 + r][j * 16 + lm] = (ushort)hs;
                PL[w][lq * 4 + r][j * 16 + lm] = (ushort)ls;
            }
        }

        // ---- PV phase: 2 staging rounds of 64 keys (coalesced + swizzled) -
#pragma unroll
        for (int g = 0; g < 2; g++) {
            __syncthreads();
#pragma unroll
            for (int p = 0; p < 4; p++) {
                int e = t + p * 256;
                int att = e >> 3, gidx = e & 7;
                int key = kc + g * 64 + gidx * 8; // < 640 = MPAD, always in buf
                short8 vh = *(const short8*)(Vhz + (long)att * MPAD + key);
                short8 vl = *(const short8*)(Vlz + (long)att * MPAD + key);
                int sw = (gidx ^ (att & 7)) * 8;
                *(short8*)&SB[0][att][sw] = vh;
                *(short8*)&SB[1][att][sw] = vl;
            }
            __syncthreads();
#pragma unroll
            for (int kk = 0; kk < 2; kk++) {
                short8 ph = *(const short8*)&PH[w][lm][g * 64 + kk * 32 + lq * 8];
                short8 pl = *(const short8*)&PL[w][lm][g * 64 + kk * 32 + lq * 8];
#pragma unroll
                for (int j = 0; j < 8; j++) {
                    int row = j * 16 + lm;
                    int sw = ((kk * 4 + lq) ^ (lm & 7)) * 8;
                    short8 vh = *(const short8*)&SB[0][row][sw];
                    short8 vl = *(const short8*)&SB[1][row][sw];
                    oacc[j] = __builtin_amdgcn_mfma_f32_16x16x32_bf16(ph, vh, oacc[j], 0, 0, 0);
                    oacc[j] = __builtin_amdgcn_mfma_f32_16x16x32_bf16(ph, vl, oacc[j], 0, 0, 0);
                    oacc[j] = __builtin_amdgcn_mfma_f32_16x16x32_bf16(pl, vh, oacc[j], 0, 0, 0);
                }
            }
        }
    }

    // ---- row sums, then packed bf16 hi/lo store ----
#pragma unroll
    for (int mk = 1; mk <= 8; mk <<= 1)
#pragma unroll
        for (int r = 0; r < 4; r++) {
            Er[r] += __shfl_xor(Er[r], mk, 64);
            Sr[r] += __shfl_xor(Sr[r], mk, 64);
        }
    float inv[4];
#pragma unroll
    for (int r = 0; r < 4; r++) inv[r] = 1.f / (Sr[r] + 1e-8f * Er[r]);
    uint* Oz = OB + (long)z * Mc * ATTc;
#pragma unroll
    for (int j = 0; j < 8; j++)
#pragma unroll
        for (int r = 0; r < 4; r++) {
            int row = qrow0 + lq * 4 + r;
            if (row < Mc) {
                float v = oacc[j][r] * inv[r];
                short hs, ls;
                bsplit(v, hs, ls);
                Oz[(long)row * ATTc + j * 16 + lm] =
                    ((uint)(ushort)ls << 16) | (uint)(ushort)hs;
            }
        }
}

// ---------------- Wlin^T prep: transpose + bf16 hi/lo split ----------------
__global__ __launch_bounds__(256)
void wlin_prep_k(const float* __restrict__ Wlin,
                 ushort* __restrict__ WTH, ushort* __restrict__ WTL)
{
    int i = blockIdx.x * 256 + threadIdx.x;
    if (i >= 64 * 128) return;
    int c = i >> 7, a = i & 127;
    short h, l;
    bsplit(Wlin[a * 64 + c], h, l);
    WTH[c * 128 + a] = (ushort)h;
    WTL[c * 128 + a] = (ushort)l;
}

// ---- Wlin GEMM: CUR = unpack(OB) @ Wlin + blin (split-bf16 MFMA) ----------
__global__ __launch_bounds__(256)
void wlin_k(const uint* __restrict__ OB, const ushort* __restrict__ WTH,
            const ushort* __restrict__ WTL, const float* __restrict__ blin,
            float* __restrict__ CUR, int Mtot)
{
    __shared__ __align__(16) ushort As[2][128][40];
    __shared__ __align__(16) ushort Bs[2][64][136];
    const int m0 = blockIdx.x * 128;
    const int t = threadIdx.x;
    const int lane = t & 63, w = t >> 6;
    const int wm = (w >> 1) * 64, wn = (w & 1) * 32;
    const int lm = lane & 15, lq = lane >> 4;

#pragma unroll
    for (int p = 0; p < 4; p++) {
        int e = t + p * 256;
        int row = e >> 4, seg = (e & 15) << 3;
        *(short8*)&Bs[0][row][seg] = *(const short8*)(WTH + row * 128 + seg);
        *(short8*)&Bs[1][row][seg] = *(const short8*)(WTL + row * 128 + seg);
    }

    f32x4 acc[4][2];
#pragma unroll
    for (int i = 0; i < 4; i++)
#pragma unroll
        for (int j = 0; j < 2; j++)
#pragma unroll
            for (int r = 0; r < 4; r++) acc[i][j][r] = 0.f;

    for (int k0 = 0; k0 < 128; k0 += 32) {
        __syncthreads();
#pragma unroll
        for (int p = 0; p < 2; p++) {
            int e = t + p * 256;
            int row = e >> 2, seg = (e & 3) << 3;
            int gm = m0 + row;
            short8 vh, vl;
#pragma unroll
            for (int q = 0; q < 8; q++) { vh[q] = 0; vl[q] = 0; }
            if (gm < Mtot) {
                const uint4 u0 = *(const uint4*)(OB + (long)gm * 128 + k0 + seg);
                const uint4 u1 = *(const uint4*)(OB + (long)gm * 128 + k0 + seg + 4);
#pragma unroll
                for (int q = 0; q < 4; q++) {
                    uint u = ((const uint*)&u0)[q];
                    vh[q] = (short)(u & 0xffff); vl[q] = (short)(u >> 16);
                }
#pragma unroll
                for (int q = 0; q < 4; q++) {
                    uint u = ((const uint*)&u1)[q];
                    vh[4 + q] = (short)(u & 0xffff); vl[4 + q] = (short)(u >> 16);
                }
            }
            *(short8*)&As[0][row][seg] = vh;
            *(short8*)&As[1][row][seg] = vl;
        }
        __syncthreads();

        short8 af[4][2], bf[2][2];
#pragma unroll
        for (int i = 0; i < 4; i++) {
            af[i][0] = *(const short8*)&As[0][wm + i * 16 + lm][lq * 8];
            af[i][1] = *(const short8*)&As[1][wm + i * 16 + lm][lq * 8];
        }
#pragma unroll
        for (int j = 0; j < 2; j++) {
            bf[j][0] = *(const short8*)&Bs[0][wn + j * 16 + lm][k0 + lq * 8];
            bf[j][1] = *(const short8*)&Bs[1][wn + j * 16 + lm][k0 + lq * 8];
        }
#pragma unroll
        for (int i = 0; i < 4; i++)
#pragma unroll
            for (int j = 0; j < 2; j++) {
                acc[i][j] = __builtin_amdgcn_mfma_f32_16x16x32_bf16(af[i][0], bf[j][0], acc[i][j], 0, 0, 0);
                acc[i][j] = __builtin_amdgcn_mfma_f32_16x16x32_bf16(af[i][0], bf[j][1], acc[i][j], 0, 0, 0);
                acc[i][j] = __builtin_amdgcn_mfma_f32_16x16x32_bf16(af[i][1], bf[j][0], acc[i][j], 0, 0, 0);
            }
    }
#pragma unroll
    for (int i = 0; i < 4; i++) {
        int gmb = m0 + wm + i * 16 + lq * 4;
#pragma unroll
        for (int j = 0; j < 2; j++) {
            int col = wn + j * 16 + lm;
            float b = blin[col];
#pragma unroll
            for (int r = 0; r < 4; r++) {
                int gm = gmb + r;
                if (gm < Mtot) CUR[(long)gm * 64 + col] = acc[i][j][r] + b;
            }
        }
    }
}

// ---------------- running max of middle-window slice [2N:3N] ---------------
__global__ __launch_bounds__(256)
void cand_update_k(const float* __restrict__ cur, float* __restrict__ cand,
                   int bw0, long total, int first)
{
    long idx = (long)blockIdx.x * 256 + threadIdx.x;
    if (idx >= total) return;
    int c = (int)(idx & 63);
    long r = idx >> 6;
    int n = (int)(r % Nc);
    int i = (int)(r / Nc);
    long bw = bw0 + i;
    float v = cur[((bw * Mc) + 2 * Nc + n) * Cc + c];
    long o = ((bw * Nc) + n) * Cc + c;
    cand[o] = first ? v : fmaxf(cand[o], v);
}

// ---------------- output layer ----------------
__global__ __launch_bounds__(128)
void output_k(const float* __restrict__ h2, const float* __restrict__ Wo,
              const float* __restrict__ bo, float* __restrict__ out)
{
    __shared__ float ds[512];
    int row = blockIdx.x;
    int b = row / Nc, n = row % Nc;
    int t = threadIdx.x;
    for (int e = t; e < 512; e += 128) {
        int tt = e >> 6, c = e & 63;
        ds[e] = h2[(((long)b * 8 + tt) * Nc + n) * Cc + c];
    }
    __syncthreads();
    float acc = bo[t];
    for (int e = 0; e < 512; e++) acc += ds[e] * Wo[e * OUTFc + t];
    acc = fmaxf(acc, 0.f);
    for (int p = 0; p < PREDc; p++)
        out[(((long)b * PREDc + p) * Nc + n) * (long)OUTFc + t] = acc;
}

extern "C" void kernel_launch(void* const* d_in, const int* in_sizes, int n_in,
                              void* d_out, int out_size, void* d_ws, size_t ws_size,
                              hipStream_t stream)
{
    (void)in_sizes; (void)n_in; (void)out_size; (void)ws_size;
    const float* x     = (const float*)d_in[0];
    const float* Wqkv  = (const float*)d_in[4];
    const float* bqkv  = (const float*)d_in[5];
    const float* Wlin  = (const float*)d_in[6];
    const float* blin  = (const float*)d_in[7];
    const float* Wa    = (const float*)d_in[8];
    const float* Wb    = (const float*)d_in[9];
    const float* temb0 = (const float*)d_in[13];
    const float* temb1 = (const float*)d_in[14];
    const float* semb  = (const float*)d_in[15];
    const float* Wo    = (const float*)d_in[16];
    const float* bo    = (const float*)d_in[17];
    float* out = (float*)d_out;

    // ---- workspace (float offsets), ~60 MB ----
    float* ws   = (float*)d_ws;
    float* CUR  = ws;                                  // 1,536,000
    float* ADJ  = CUR + (long)MAXBW * Mc * Cc;         // 360,000
    float* CAND = ADJ + (long)Mc * Mc;                 // 512,000
    uint*  OB   = (uint*)(CAND + (long)MAXBW * Nc * Cc); // 3,072,000 u32
    float* QHf  = (float*)(OB + (long)MAXBW * Mc * ATTc);
    const long QSZ = (long)MAXBW * Mc * ATTc / 2;      // in floats
    float* QLf  = QHf + QSZ;
    float* KHf  = QLf + QSZ;
    float* KLf  = KHf + QSZ;
    float* VTHf = KLf + QSZ;
    float* VTLf = VTHf + (long)MAXBW * ATTc * MPAD / 2;
    ushort* NAH = (ushort*)(VTLf + (long)MAXBW * ATTc * MPAD / 2);
    ushort* NAL = NAH + Mc * Cc;
    ushort* NBH = NAL + Mc * Cc;
    ushort* NBL = NBH + Mc * Cc;
    ushort* WTH = NBL + Mc * Cc;                       // 64*128 each
    ushort* WTL = WTH + 64 * 128;

    ushort* QH  = (ushort*)QHf;
    ushort* QL  = (ushort*)QLf;
    ushort* KH  = (ushort*)KHf;
    ushort* KL  = (ushort*)KLf;
    ushort* VTH = (ushort*)VTHf;
    ushort* VTL = (ushort*)VTLf;

    const float inv_sqrt_att = 0.08838834764831845f;   // 1/sqrt(128)

    // Wlin^T hi/lo (weights constant across iterations)
    wlin_prep_k<<<dim3(32), dim3(256), 0, stream>>>(Wlin, WTH, WTL);

    for (int layer = 0; layer < 2; layer++) {
        int Tin = layer ? 10 : 12;
        int nw  = Tin - 2;
        int BW  = Bc * nw;                             // 40 then 32
        int Mtot = BW * Mc;
        const float* src  = layer ? CAND : x;
        const float* temb = layer ? temb1 : temb0;

        long etotal = (long)BW * Mc * Cc;
        embed_window_k<<<dim3((unsigned)((etotal + 255) / 256)), dim3(256), 0, stream>>>(
            src, temb, semb, CUR, Tin, nw, etotal);

        for (int it = 0; it < 3; it++) {
            // adjacency: mean -> NA/NB (bf16 split) -> sigmoid MFMA
            mean_nab_k<<<dim3(38), dim3(256), 0, stream>>>(
                CUR, Wa, Wb, NAH, NAL, NBH, NBL, BW);
            adjmm_k<<<dim3(5, 5), dim3(256), 0, stream>>>(
                NAH, NAL, NBH, NBL, ADJ);

            // QKV projection + hi/lo split (XCD-swizzled)
            qkv_split_k<<<dim3(BW * 15), dim3(256), 0, stream>>>(
                CUR, Wqkv, bqkv, QH, QL, KH, KL, VTH, VTL);

            // fused attention (R13 config + swizzled SB)
            attn_k<<<dim3(BW * 10), dim3(256), 0, stream>>>(
                QH, QL, KH, KL, VTH, VTL, ADJ, OB, inv_sqrt_att);

            // cur = O @ Wlin + blin (split-bf16 MFMA)
            wlin_k<<<dim3((Mtot + 127) / 128), dim3(256), 0, stream>>>(
                OB, WTH, WTL, blin, CUR, Mtot);

            // running max of middle window
            long mtot = (long)BW * Nc * Cc;
            cand_update_k<<<dim3((unsigned)((mtot + 255) / 256)), dim3(256), 0, stream>>>(
                CUR, CAND, 0, mtot, it == 0 ? 1 : 0);
        }
    }
    output_k<<<dim3(Bc * Nc), dim3(128), 0, stream>>>(CAND, Wo, bo, out);
}

// Round 16
// 904.601 us; speedup vs baseline: 1.2558x; 1.0132x over previous
//
#include <hip/hip_runtime.h>
#include <hip/hip_bf16.h>
#include <math.h>

constexpr int Bc   = 4;
constexpr int Nc   = 200;
constexpr int Cc   = 64;
constexpr int Mc   = 600;    // 3*N
constexpr int ATTc = 128;
constexpr int OUTFc = 128;
constexpr int PREDc = 12;
constexpr int MAXBW = 40;
constexpr int MPAD  = 640;   // padded V^T leading dim

typedef short short4v __attribute__((ext_vector_type(4)));
typedef short short8 __attribute__((ext_vector_type(8)));
typedef float f32x4  __attribute__((ext_vector_type(4)));

static __device__ __forceinline__ void bsplit(float v, short& h, short& l) {
    __hip_bfloat16 hb = __float2bfloat16(v);
    float hf = __bfloat162float(hb);
    __hip_bfloat16 lb = __float2bfloat16(v - hf);
    h = *(short*)&hb; l = *(short*)&lb;
}

// ---------------- embed + sliding window ----------------
__global__ __launch_bounds__(256)
void embed_window_k(const float* __restrict__ src, const float* __restrict__ temb,
                    const float* __restrict__ semb, float* __restrict__ dst,
                    int Tin, int nw, long total)
{
    long idx = (long)blockIdx.x * 256 + threadIdx.x;
    if (idx >= total) return;
    int c = (int)(idx & 63);
    long r = idx >> 6;
    int n = (int)(r % Nc); r /= Nc;
    int j = (int)(r % 3);  r /= 3;
    int w = (int)(r % nw);
    int b = (int)(r / nw);
    int t = w + j;
    dst[idx] = src[(((long)b * Tin + t) * Nc + n) * Cc + c]
             + temb[t * Cc + c] + semb[n * Cc + c];
}

// ------- fused node-mean + NA/NB projection -> bf16 hi/lo outputs ---------
__global__ __launch_bounds__(256)
void mean_nab_k(const float* __restrict__ cur, const float* __restrict__ Wa,
                const float* __restrict__ Wb,
                ushort* __restrict__ NAH, ushort* __restrict__ NAL,
                ushort* __restrict__ NBH, ushort* __restrict__ NBL, int BW)
{
    __shared__ float Ns[64][17];   // [k][row]
    __shared__ float Ws[64][132];  // [k][ Wa | Wb ]
    const int m0 = blockIdx.x * 16;
    const int t = threadIdx.x;
    for (int e = t; e < 1024; e += 256) {
        int r = e >> 4, c4 = (e & 15) << 2;
        *(float4*)&Ws[r][c4]      = *(const float4*)&Wa[r * 64 + c4];
        *(float4*)&Ws[r][64 + c4] = *(const float4*)&Wb[r * 64 + c4];
    }
    {
        int row = t >> 4, c4 = (t & 15) << 2;
        int gm = m0 + row;
        float4 sv = make_float4(0.f, 0.f, 0.f, 0.f);
        if (gm < Mc) {
            for (int bw = 0; bw < BW; bw++) {
                const float4 v = *(const float4*)&cur[((long)bw * Mc + gm) * Cc + c4];
                sv.x += v.x; sv.y += v.y; sv.z += v.z; sv.w += v.w;
            }
        }
        const float inv = 1.f / BW;
        Ns[c4 + 0][row] = sv.x * inv; Ns[c4 + 1][row] = sv.y * inv;
        Ns[c4 + 2][row] = sv.z * inv; Ns[c4 + 3][row] = sv.w * inv;
    }
    __syncthreads();
    const int row = t >> 4, c8 = (t & 15) * 8;
    float acc[8] = {};
    for (int k = 0; k < 64; k++) {
        float a = Ns[k][row];
        float b[8];
        *(float4*)&b[0] = *(const float4*)&Ws[k][c8];
        *(float4*)&b[4] = *(const float4*)&Ws[k][c8 + 4];
#pragma unroll
        for (int j = 0; j < 8; j++) acc[j] += a * b[j];
    }
    int gm = m0 + row;
    if (gm < Mc) {
#pragma unroll
        for (int j = 0; j < 8; j++) {
            int col = c8 + j;
            short h, l;
            bsplit(acc[j], h, l);
            if (col < 64) { NAH[gm * 64 + col] = (ushort)h; NAL[gm * 64 + col] = (ushort)l; }
            else { NBH[gm * 64 + col - 64] = (ushort)h; NBL[gm * 64 + col - 64] = (ushort)l; }
        }
    }
}

// ---- adj = sigmoid( (NA NB^T) / 8 ): split-bf16 MFMA, 128-tiles, grid 5x5 -
__global__ __launch_bounds__(256)
void adjmm_k(const ushort* __restrict__ Ah, const ushort* __restrict__ Al,
             const ushort* __restrict__ Bh, const ushort* __restrict__ Bl,
             float* __restrict__ ADJ)
{
    __shared__ __align__(16) ushort As[2][128][40];
    __shared__ __align__(16) ushort Bs[2][128][40];
    const int m0 = blockIdx.y * 128, n0 = blockIdx.x * 128;
    const int t = threadIdx.x;
    const int lane = t & 63, w = t >> 6;
    const int wm = (w >> 1) * 64, wn = (w & 1) * 64;
    const int lm = lane & 15, lq = lane >> 4;

    f32x4 acc[4][4];
#pragma unroll
    for (int i = 0; i < 4; i++)
#pragma unroll
        for (int j = 0; j < 4; j++)
#pragma unroll
            for (int r = 0; r < 4; r++) acc[i][j][r] = 0.f;

    for (int k0 = 0; k0 < 64; k0 += 32) {
        __syncthreads();
#pragma unroll
        for (int p = 0; p < 2; p++) {
            int e = t + p * 256;
            int row = e >> 2, ks = (e & 3) << 3;
            {
                int gm = m0 + row;
                short8 vh, vl;
#pragma unroll
                for (int q = 0; q < 8; q++) { vh[q] = 0; vl[q] = 0; }
                if (gm < Mc) {
                    vh = *(const short8*)(Ah + (long)gm * 64 + k0 + ks);
                    vl = *(const short8*)(Al + (long)gm * 64 + k0 + ks);
                }
                *(short8*)&As[0][row][ks] = vh;
                *(short8*)&As[1][row][ks] = vl;
            }
            {
                int gn = n0 + row;
                short8 vh, vl;
#pragma unroll
                for (int q = 0; q < 8; q++) { vh[q] = 0; vl[q] = 0; }
                if (gn < Mc) {
                    vh = *(const short8*)(Bh + (long)gn * 64 + k0 + ks);
                    vl = *(const short8*)(Bl + (long)gn * 64 + k0 + ks);
                }
                *(short8*)&Bs[0][row][ks] = vh;
                *(short8*)&Bs[1][row][ks] = vl;
            }
        }
        __syncthreads();

        short8 af[4][2], bf[4][2];
#pragma unroll
        for (int i = 0; i < 4; i++) {
            af[i][0] = *(const short8*)&As[0][wm + i * 16 + lm][lq * 8];
            af[i][1] = *(const short8*)&As[1][wm + i * 16 + lm][lq * 8];
        }
#pragma unroll
        for (int j = 0; j < 4; j++) {
            bf[j][0] = *(const short8*)&Bs[0][wn + j * 16 + lm][lq * 8];
            bf[j][1] = *(const short8*)&Bs[1][wn + j * 16 + lm][lq * 8];
        }
#pragma unroll
        for (int i = 0; i < 4; i++)
#pragma unroll
            for (int j = 0; j < 4; j++) {
                acc[i][j] = __builtin_amdgcn_mfma_f32_16x16x32_bf16(af[i][0], bf[j][0], acc[i][j], 0, 0, 0);
                acc[i][j] = __builtin_amdgcn_mfma_f32_16x16x32_bf16(af[i][0], bf[j][1], acc[i][j], 0, 0, 0);
                acc[i][j] = __builtin_amdgcn_mfma_f32_16x16x32_bf16(af[i][1], bf[j][0], acc[i][j], 0, 0, 0);
            }
    }
#pragma unroll
    for (int i = 0; i < 4; i++) {
        int gmb = m0 + wm + i * 16 + lq * 4;
#pragma unroll
        for (int j = 0; j < 4; j++) {
            int gn = n0 + wn + j * 16 + lm;
            if (gn >= Mc) continue;
#pragma unroll
            for (int r = 0; r < 4; r++) {
                int gm = gmb + r;
                if (gm < Mc)
                    ADJ[(long)gm * Mc + gn] = 1.f / (1.f + __expf(-acc[i][j][r] * 0.125f));
            }
        }
    }
}

// ---------------- Wqkv^T prep: transpose + bf16 hi/lo split ----------------
// WQH/WQL [384][64]: row = output column of Wqkv, col = input channel.
__global__ __launch_bounds__(256)
void wqkv_prep_k(const float* __restrict__ Wqkv,
                 ushort* __restrict__ WQH, ushort* __restrict__ WQL)
{
    int i = blockIdx.x * 256 + threadIdx.x;
    if (i >= 384 * 64) return;
    int n = i >> 6, c = i & 63;
    short h, l;
    bsplit(Wqkv[c * 384 + n], h, l);
    WQH[n * 64 + c] = (ushort)h;
    WQL[n * 64 + c] = (ushort)l;
}

// ---- QKV projection: split-bf16 MFMA, K=64, XCD-swizzled ------------------
// A = CUR tile (fp32 -> hi/lo in staging), B = WqkvT hi/lo. C routed through
// packed-uint LDS scratch so all global stores are short8 (no amplification).
__global__ __launch_bounds__(256)
void qkv_mfma_k(const float* __restrict__ CURp,
                const ushort* __restrict__ WQH, const ushort* __restrict__ WQL,
                const float* __restrict__ bias,
                ushort* __restrict__ QH, ushort* __restrict__ QL,
                ushort* __restrict__ KH, ushort* __restrict__ KL,
                ushort* __restrict__ VTH, ushort* __restrict__ VTL)
{
    __shared__ __align__(16) ushort SM[36864];   // 72 KB, multi-purpose
    ushort* AsH = SM;                 // [128][72]
    ushort* AsL = SM + 9216;
    ushort* BsH = SM + 18432;
    ushort* BsL = SM + 27648;
    const int bid = blockIdx.x;
    const int xcd = bid & 7, slot = bid >> 3;
    const int z = (slot / 15) * 8 + xcd;
    const int r15 = slot % 15;
    const int which = r15 % 3;             // 0=q 1=k 2=v
    const int m0 = (r15 / 3) * 128;
    const int nb = which * 128;
    const float* A = CURp + (long)z * Mc * Cc;
    const int t = threadIdx.x;
    const int lane = t & 63, w = t >> 6;
    const int wm = (w >> 1) * 64, wn = (w & 1) * 64;
    const int lm = lane & 15, lq = lane >> 4;

    // ---- stage A: CUR tile 128 rows x 64 k, fp32 -> hi/lo ----
#pragma unroll
    for (int p = 0; p < 8; p++) {
        int e = t + p * 256;              // 0..2047
        int row = e >> 4, k4 = (e & 15) * 4;
        int gm = m0 + row;
        float4 v = make_float4(0.f, 0.f, 0.f, 0.f);
        if (gm < Mc) v = *(const float4*)(A + (long)gm * 64 + k4);
        short4v h4, l4;
        short hs, ls;
        bsplit(v.x, hs, ls); h4[0] = hs; l4[0] = ls;
        bsplit(v.y, hs, ls); h4[1] = hs; l4[1] = ls;
        bsplit(v.z, hs, ls); h4[2] = hs; l4[2] = ls;
        bsplit(v.w, hs, ls); h4[3] = hs; l4[3] = ls;
        *(short4v*)(AsH + row * 72 + k4) = h4;
        *(short4v*)(AsL + row * 72 + k4) = l4;
    }
    // ---- stage B: WqkvT rows nb..nb+127 x 64 ----
#pragma unroll
    for (int p = 0; p < 4; p++) {
        int e = t + p * 256;              // 0..1023
        int row = e >> 3, seg = (e & 7) * 8;
        *(short8*)(BsH + row * 72 + seg) = *(const short8*)(WQH + (long)(nb + row) * 64 + seg);
        *(short8*)(BsL + row * 72 + seg) = *(const short8*)(WQL + (long)(nb + row) * 64 + seg);
    }
    __syncthreads();

    f32x4 acc[4][4];
#pragma unroll
    for (int i = 0; i < 4; i++)
#pragma unroll
        for (int j = 0; j < 4; j++)
#pragma unroll
            for (int r = 0; r < 4; r++) acc[i][j][r] = 0.f;

#pragma unroll
    for (int ks = 0; ks < 2; ks++) {
        short8 af[4][2], bf[4][2];
#pragma unroll
        for (int i = 0; i < 4; i++) {
            af[i][0] = *(const short8*)(AsH + (wm + i * 16 + lm) * 72 + ks * 32 + lq * 8);
            af[i][1] = *(const short8*)(AsL + (wm + i * 16 + lm) * 72 + ks * 32 + lq * 8);
        }
#pragma unroll
        for (int j = 0; j < 4; j++) {
            bf[j][0] = *(const short8*)(BsH + (wn + j * 16 + lm) * 72 + ks * 32 + lq * 8);
            bf[j][1] = *(const short8*)(BsL + (wn + j * 16 + lm) * 72 + ks * 32 + lq * 8);
        }
#pragma unroll
        for (int i = 0; i < 4; i++)
#pragma unroll
            for (int j = 0; j < 4; j++) {
                acc[i][j] = __builtin_amdgcn_mfma_f32_16x16x32_bf16(af[i][0], bf[j][0], acc[i][j], 0, 0, 0);
                acc[i][j] = __builtin_amdgcn_mfma_f32_16x16x32_bf16(af[i][0], bf[j][1], acc[i][j], 0, 0, 0);
                acc[i][j] = __builtin_amdgcn_mfma_f32_16x16x32_bf16(af[i][1], bf[j][0], acc[i][j], 0, 0, 0);
            }
    }
    __syncthreads();   // frags consumed; SM reused as C scratch

    // ---- C -> packed (hi|lo) uint LDS scratch, stride 132 ----
    uint* CP = (uint*)SM;                 // [128][132] uints = 67.6 KB
#pragma unroll
    for (int i = 0; i < 4; i++)
#pragma unroll
        for (int j = 0; j < 4; j++) {
            int col = wn + j * 16 + lm;
            float b = bias[nb + col];
#pragma unroll
            for (int r = 0; r < 4; r++) {
                int row = wm + i * 16 + lq * 4 + r;
                float v = acc[i][j][r] + b;
                if (which == 2) v = fmaxf(v, 0.f);
                short hs, ls;
                bsplit(v, hs, ls);
                CP[row * 132 + col] = ((uint)(ushort)ls << 16) | (uint)(ushort)hs;
            }
        }
    __syncthreads();

    if (which == 2) {
        // V: transposed packed store [col][MPAD] + row
        ushort* vh = VTH + (long)z * ATTc * MPAD;
        ushort* vl = VTL + (long)z * ATTc * MPAD;
#pragma unroll
        for (int p = 0; p < 8; p++) {
            int e = t + p * 256;          // 0..2047
            int col = e >> 4, rg = (e & 15) * 8;
            if (m0 + rg < Mc) {           // 600 % 8 == 0: whole group valid
                short8 h8, l8;
#pragma unroll
                for (int q = 0; q < 8; q++) {
                    uint u = CP[(rg + q) * 132 + col];
                    h8[q] = (short)(u & 0xffff);
                    l8[q] = (short)(u >> 16);
                }
                *(short8*)(vh + (long)col * MPAD + m0 + rg) = h8;
                *(short8*)(vl + (long)col * MPAD + m0 + rg) = l8;
            }
        }
    } else {
        // Q/K: row-major packed store [row][128]
        ushort* dh = (which == 0 ? QH : KH) + (long)z * Mc * ATTc;
        ushort* dl = (which == 0 ? QL : KL) + (long)z * Mc * ATTc;
#pragma unroll
        for (int p = 0; p < 8; p++) {
            int e = t + p * 256;
            int row = e >> 4, seg = (e & 15) * 8;
            int gm = m0 + row;
            if (gm < Mc) {
                short8 h8, l8;
#pragma unroll
                for (int q = 0; q < 8; q++) {
                    uint u = CP[row * 132 + seg + q];
                    h8[q] = (short)(u & 0xffff);
                    l8[q] = (short)(u >> 16);
                }
                *(short8*)(dh + (long)gm * ATTc + seg) = h8;
                *(short8*)(dl + (long)gm * ATTc + seg) = l8;
            }
        }
    }
}

// ---- fused attention (R13-proven): S=QK^T -> P=exp(s)*adj -> PV -----------
// Grid BW*10 XCD-swizzled, 64 q-rows/block, 4 waves x 16 rows, K/V LDS-staged,
// P wave-private. O stored as packed bf16 hi/lo pairs (uint32) for wlin MFMA.
__global__ __launch_bounds__(256)
void attn_k(const ushort* __restrict__ QH, const ushort* __restrict__ QL,
            const ushort* __restrict__ KH, const ushort* __restrict__ KL,
            const ushort* __restrict__ VTH, const ushort* __restrict__ VTL,
            const float* __restrict__ adj, uint* __restrict__ OB, float scale)
{
    __shared__ __align__(16) ushort SB[2][128][72];   // K or V stage (64 k)
    __shared__ __align__(16) ushort PH[4][16][152];   // wave-private P hi
    __shared__ __align__(16) ushort PL[4][16][152];   //                lo
    const int bid = blockIdx.x;
    const int xcd = bid & 7, slot = bid >> 3;
    const int z = (slot / 10) * 8 + xcd;
    const int m0 = (slot % 10) * 64;
    const int t = threadIdx.x;
    const int lane = t & 63, w = t >> 6;
    const int lm = lane & 15, lq = lane >> 4;
    const int qrow0 = m0 + w * 16;

    const ushort* Qhz = QH + (long)z * Mc * ATTc;
    const ushort* Qlz = QL + (long)z * Mc * ATTc;
    const ushort* Khz = KH + (long)z * Mc * ATTc;
    const ushort* Klz = KL + (long)z * Mc * ATTc;
    const ushort* Vhz = VTH + (long)z * ATTc * MPAD;
    const ushort* Vlz = VTL + (long)z * ATTc * MPAD;

    short8 qh[4], ql[4];
    {
        int qr = qrow0 + lm;
        if (qr < Mc) {
            const ushort* qp = Qhz + (long)qr * ATTc;
            const ushort* qp2 = Qlz + (long)qr * ATTc;
#pragma unroll
            for (int ks = 0; ks < 4; ks++) {
                qh[ks] = *(const short8*)(qp + ks * 32 + lq * 8);
                ql[ks] = *(const short8*)(qp2 + ks * 32 + lq * 8);
            }
        } else {
#pragma unroll
            for (int ks = 0; ks < 4; ks++)
#pragma unroll
                for (int q = 0; q < 8; q++) { qh[ks][q] = 0; ql[ks][q] = 0; }
        }
    }

    f32x4 oacc[8];
#pragma unroll
    for (int j = 0; j < 8; j++)
#pragma unroll
        for (int r = 0; r < 4; r++) oacc[j][r] = 0.f;
    float Er[4] = {}, Sr[4] = {};

    for (int kc = 0; kc < 640; kc += 128) {       // 5 key chunks
        f32x4 sacc[8];
#pragma unroll
        for (int j = 0; j < 8; j++)
#pragma unroll
            for (int r = 0; r < 4; r++) sacc[j][r] = 0.f;

        // ---- QK phase: 2 staging rounds of 64 att ----
#pragma unroll
        for (int g = 0; g < 2; g++) {
            __syncthreads();
#pragma unroll
            for (int p = 0; p < 4; p++) {
                int e = t + p * 256;              // 0..1023
                int row = e >> 3, ks = (e & 7) << 3;
                int key = kc + row;
                short8 vh, vl;
#pragma unroll
                for (int q = 0; q < 8; q++) { vh[q] = 0; vl[q] = 0; }
                if (key < Mc) {
                    vh = *(const short8*)(Khz + (long)key * ATTc + g * 64 + ks);
                    vl = *(const short8*)(Klz + (long)key * ATTc + g * 64 + ks);
                }
                *(short8*)&SB[0][row][ks] = vh;
                *(short8*)&SB[1][row][ks] = vl;
            }
            __syncthreads();
#pragma unroll
            for (int kk = 0; kk < 2; kk++) {
                int ks = g * 2 + kk;
#pragma unroll
                for (int j = 0; j < 8; j++) {
                    short8 bh = *(const short8*)&SB[0][j * 16 + lm][kk * 32 + lq * 8];
                    short8 bl = *(const short8*)&SB[1][j * 16 + lm][kk * 32 + lq * 8];
                    sacc[j] = __builtin_amdgcn_mfma_f32_16x16x32_bf16(qh[ks], bh, sacc[j], 0, 0, 0);
                    sacc[j] = __builtin_amdgcn_mfma_f32_16x16x32_bf16(qh[ks], bl, sacc[j], 0, 0, 0);
                    sacc[j] = __builtin_amdgcn_mfma_f32_16x16x32_bf16(ql[ks], bh, sacc[j], 0, 0, 0);
                }
            }
        }

        // ---- epilogue: P = exp(s*scale)*adj -> wave-private LDS ----
#pragma unroll
        for (int j = 0; j < 8; j++) {
            int col = kc + j * 16 + lm;
            bool cok = col < Mc;
#pragma unroll
            for (int r = 0; r < 4; r++) {
                int row = qrow0 + lq * 4 + r;
                float e = cok ? __expf(sacc[j][r] * scale) : 0.f;
                float a = (cok && row < Mc) ? adj[(long)row * Mc + col] : 0.f;
                float p = e * a;
                Er[r] += e; Sr[r] += p;
                short hs, ls;
                bsplit(p, hs, ls);
                PH[w][lq * 4 + r][j * 16 + lm] = (ushort)hs;
                PL[w][lq * 4 + r][j * 16 + lm] = (ushort)ls;
            }
        }

        // ---- PV phase: 2 staging rounds of 64 keys ----
#pragma unroll
        for (int g = 0; g < 2; g++) {
            __syncthreads();
#pragma unroll
            for (int p = 0; p < 4; p++) {
                int e = t + p * 256;
                int att = e >> 3, ks = (e & 7) << 3;
                int key = kc + g * 64 + ks;       // < 640 = MPAD, always in buf
                short8 vh = *(const short8*)(Vhz + (long)att * MPAD + key);
                short8 vl = *(const short8*)(Vlz + (long)att * MPAD + key);
                *(short8*)&SB[0][att][ks] = vh;
                *(short8*)&SB[1][att][ks] = vl;
            }
            __syncthreads();
#pragma unroll
            for (int kk = 0; kk < 2; kk++) {
                short8 ph = *(const short8*)&PH[w][lm][g * 64 + kk * 32 + lq * 8];
                short8 pl = *(const short8*)&PL[w][lm][g * 64 + kk * 32 + lq * 8];
#pragma unroll
                for (int j = 0; j < 8; j++) {
                    short8 vh = *(const short8*)&SB[0][j * 16 + lm][kk * 32 + lq * 8];
                    short8 vl = *(const short8*)&SB[1][j * 16 + lm][kk * 32 + lq * 8];
                    oacc[j] = __builtin_amdgcn_mfma_f32_16x16x32_bf16(ph, vh, oacc[j], 0, 0, 0);
                    oacc[j] = __builtin_amdgcn_mfma_f32_16x16x32_bf16(ph, vl, oacc[j], 0, 0, 0);
                    oacc[j] = __builtin_amdgcn_mfma_f32_16x16x32_bf16(pl, vh, oacc[j], 0, 0, 0);
                }
            }
        }
    }

    // ---- row sums, then packed bf16 hi/lo store ----
#pragma unroll
    for (int mk = 1; mk <= 8; mk <<= 1)
#pragma unroll
        for (int r = 0; r < 4; r++) {
            Er[r] += __shfl_xor(Er[r], mk, 64);
            Sr[r] += __shfl_xor(Sr[r], mk, 64);
        }
    float inv[4];
#pragma unroll
    for (int r = 0; r < 4; r++) inv[r] = 1.f / (Sr[r] + 1e-8f * Er[r]);
    uint* Oz = OB + (long)z * Mc * ATTc;
#pragma unroll
    for (int j = 0; j < 8; j++)
#pragma unroll
        for (int r = 0; r < 4; r++) {
            int row = qrow0 + lq * 4 + r;
            if (row < Mc) {
                float v = oacc[j][r] * inv[r];
                short hs, ls;
                bsplit(v, hs, ls);
                Oz[(long)row * ATTc + j * 16 + lm] =
                    ((uint)(ushort)ls << 16) | (uint)(ushort)hs;
            }
        }
}

// ---------------- Wlin^T prep: transpose + bf16 hi/lo split ----------------
__global__ __launch_bounds__(256)
void wlin_prep_k(const float* __restrict__ Wlin,
                 ushort* __restrict__ WTH, ushort* __restrict__ WTL)
{
    int i = blockIdx.x * 256 + threadIdx.x;
    if (i >= 64 * 128) return;
    int c = i >> 7, a = i & 127;
    short h, l;
    bsplit(Wlin[a * 64 + c], h, l);
    WTH[c * 128 + a] = (ushort)h;
    WTL[c * 128 + a] = (ushort)l;
}

// ---- Wlin GEMM: CUR = unpack(OB) @ Wlin + blin (split-bf16 MFMA) ----------
__global__ __launch_bounds__(256)
void wlin_k(const uint* __restrict__ OB, const ushort* __restrict__ WTH,
            const ushort* __restrict__ WTL, const float* __restrict__ blin,
            float* __restrict__ CUR, int Mtot)
{
    __shared__ __align__(16) ushort As[2][128][40];
    __shared__ __align__(16) ushort Bs[2][64][136];
    const int m0 = blockIdx.x * 128;
    const int t = threadIdx.x;
    const int lane = t & 63, w = t >> 6;
    const int wm = (w >> 1) * 64, wn = (w & 1) * 32;
    const int lm = lane & 15, lq = lane >> 4;

#pragma unroll
    for (int p = 0; p < 4; p++) {
        int e = t + p * 256;
        int row = e >> 4, seg = (e & 15) << 3;
        *(short8*)&Bs[0][row][seg] = *(const short8*)(WTH + row * 128 + seg);
        *(short8*)&Bs[1][row][seg] = *(const short8*)(WTL + row * 128 + seg);
    }

    f32x4 acc[4][2];
#pragma unroll
    for (int i = 0; i < 4; i++)
#pragma unroll
        for (int j = 0; j < 2; j++)
#pragma unroll
            for (int r = 0; r < 4; r++) acc[i][j][r] = 0.f;

    for (int k0 = 0; k0 < 128; k0 += 32) {
        __syncthreads();
#pragma unroll
        for (int p = 0; p < 2; p++) {
            int e = t + p * 256;
            int row = e >> 2, seg = (e & 3) << 3;
            int gm = m0 + row;
            short8 vh, vl;
#pragma unroll
            for (int q = 0; q < 8; q++) { vh[q] = 0; vl[q] = 0; }
            if (gm < Mtot) {
                const uint4 u0 = *(const uint4*)(OB + (long)gm * 128 + k0 + seg);
                const uint4 u1 = *(const uint4*)(OB + (long)gm * 128 + k0 + seg + 4);
#pragma unroll
                for (int q = 0; q < 4; q++) {
                    uint u = ((const uint*)&u0)[q];
                    vh[q] = (short)(u & 0xffff); vl[q] = (short)(u >> 16);
                }
#pragma unroll
                for (int q = 0; q < 4; q++) {
                    uint u = ((const uint*)&u1)[q];
                    vh[4 + q] = (short)(u & 0xffff); vl[4 + q] = (short)(u >> 16);
                }
            }
            *(short8*)&As[0][row][seg] = vh;
            *(short8*)&As[1][row][seg] = vl;
        }
        __syncthreads();

        short8 af[4][2], bf[2][2];
#pragma unroll
        for (int i = 0; i < 4; i++) {
            af[i][0] = *(const short8*)&As[0][wm + i * 16 + lm][lq * 8];
            af[i][1] = *(const short8*)&As[1][wm + i * 16 + lm][lq * 8];
        }
#pragma unroll
        for (int j = 0; j < 2; j++) {
            bf[j][0] = *(const short8*)&Bs[0][wn + j * 16 + lm][k0 + lq * 8];
            bf[j][1] = *(const short8*)&Bs[1][wn + j * 16 + lm][k0 + lq * 8];
        }
#pragma unroll
        for (int i = 0; i < 4; i++)
#pragma unroll
            for (int j = 0; j < 2; j++) {
                acc[i][j] = __builtin_amdgcn_mfma_f32_16x16x32_bf16(af[i][0], bf[j][0], acc[i][j], 0, 0, 0);
                acc[i][j] = __builtin_amdgcn_mfma_f32_16x16x32_bf16(af[i][0], bf[j][1], acc[i][j], 0, 0, 0);
                acc[i][j] = __builtin_amdgcn_mfma_f32_16x16x32_bf16(af[i][1], bf[j][0], acc[i][j], 0, 0, 0);
            }
    }
#pragma unroll
    for (int i = 0; i < 4; i++) {
        int gmb = m0 + wm + i * 16 + lq * 4;
#pragma unroll
        for (int j = 0; j < 2; j++) {
            int col = wn + j * 16 + lm;
            float b = blin[col];
#pragma unroll
            for (int r = 0; r < 4; r++) {
                int gm = gmb + r;
                if (gm < Mtot) CUR[(long)gm * 64 + col] = acc[i][j][r] + b;
            }
        }
    }
}

// ---------------- running max of middle-window slice [2N:3N] ---------------
__global__ __launch_bounds__(256)
void cand_update_k(const float* __restrict__ cur, float* __restrict__ cand,
                   int bw0, long total, int first)
{
    long idx = (long)blockIdx.x * 256 + threadIdx.x;
    if (idx >= total) return;
    int c = (int)(idx & 63);
    long r = idx >> 6;
    int n = (int)(r % Nc);
    int i = (int)(r / Nc);
    long bw = bw0 + i;
    float v = cur[((bw * Mc) + 2 * Nc + n) * Cc + c];
    long o = ((bw * Nc) + n) * Cc + c;
    cand[o] = first ? v : fmaxf(cand[o], v);
}

// ---------------- output layer ----------------
__global__ __launch_bounds__(128)
void output_k(const float* __restrict__ h2, const float* __restrict__ Wo,
              const float* __restrict__ bo, float* __restrict__ out)
{
    __shared__ float ds[512];
    int row = blockIdx.x;
    int b = row / Nc, n = row % Nc;
    int t = threadIdx.x;
    for (int e = t; e < 512; e += 128) {
        int tt = e >> 6, c = e & 63;
        ds[e] = h2[(((long)b * 8 + tt) * Nc + n) * Cc + c];
    }
    __syncthreads();
    float acc = bo[t];
    for (int e = 0; e < 512; e++) acc += ds[e] * Wo[e * OUTFc + t];
    acc = fmaxf(acc, 0.f);
    for (int p = 0; p < PREDc; p++)
        out[(((long)b * PREDc + p) * Nc + n) * (long)OUTFc + t] = acc;
}

extern "C" void kernel_launch(void* const* d_in, const int* in_sizes, int n_in,
                              void* d_out, int out_size, void* d_ws, size_t ws_size,
                              hipStream_t stream)
{
    (void)in_sizes; (void)n_in; (void)out_size; (void)ws_size;
    const float* x     = (const float*)d_in[0];
    const float* Wqkv  = (const float*)d_in[4];
    const float* bqkv  = (const float*)d_in[5];
    const float* Wlin  = (const float*)d_in[6];
    const float* blin  = (const float*)d_in[7];
    const float* Wa    = (const float*)d_in[8];
    const float* Wb    = (const float*)d_in[9];
    const float* temb0 = (const float*)d_in[13];
    const float* temb1 = (const float*)d_in[14];
    const float* semb  = (const float*)d_in[15];
    const float* Wo    = (const float*)d_in[16];
    const float* bo    = (const float*)d_in[17];
    float* out = (float*)d_out;

    // ---- workspace (float offsets), ~60 MB ----
    float* ws   = (float*)d_ws;
    float* CUR  = ws;                                  // 1,536,000
    float* ADJ  = CUR + (long)MAXBW * Mc * Cc;         // 360,000
    float* CAND = ADJ + (long)Mc * Mc;                 // 512,000
    uint*  OB   = (uint*)(CAND + (long)MAXBW * Nc * Cc); // 3,072,000 u32
    float* QHf  = (float*)(OB + (long)MAXBW * Mc * ATTc);
    const long QSZ = (long)MAXBW * Mc * ATTc / 2;      // in floats
    float* QLf  = QHf + QSZ;
    float* KHf  = QLf + QSZ;
    float* KLf  = KHf + QSZ;
    float* VTHf = KLf + QSZ;
    float* VTLf = VTHf + (long)MAXBW * ATTc * MPAD / 2;
    ushort* NAH = (ushort*)(VTLf + (long)MAXBW * ATTc * MPAD / 2);
    ushort* NAL = NAH + Mc * Cc;
    ushort* NBH = NAL + Mc * Cc;
    ushort* NBL = NBH + Mc * Cc;
    ushort* WTH = NBL + Mc * Cc;                       // 64*128 each
    ushort* WTL = WTH + 64 * 128;
    ushort* WQH = WTL + 64 * 128;                      // 384*64 each
    ushort* WQL = WQH + 384 * 64;

    ushort* QH  = (ushort*)QHf;
    ushort* QL  = (ushort*)QLf;
    ushort* KH  = (ushort*)KHf;
    ushort* KL  = (ushort*)KLf;
    ushort* VTH = (ushort*)VTHf;
    ushort* VTL = (ushort*)VTLf;

    const float inv_sqrt_att = 0.08838834764831845f;   // 1/sqrt(128)

    // weight preps (constant across iterations)
    wlin_prep_k<<<dim3(32), dim3(256), 0, stream>>>(Wlin, WTH, WTL);
    wqkv_prep_k<<<dim3(96), dim3(256), 0, stream>>>(Wqkv, WQH, WQL);

    for (int layer = 0; layer < 2; layer++) {
        int Tin = layer ? 10 : 12;
        int nw  = Tin - 2;
        int BW  = Bc * nw;                             // 40 then 32
        int Mtot = BW * Mc;
        const float* src  = layer ? CAND : x;
        const float* temb = layer ? temb1 : temb0;

        long etotal = (long)BW * Mc * Cc;
        embed_window_k<<<dim3((unsigned)((etotal + 255) / 256)), dim3(256), 0, stream>>>(
            src, temb, semb, CUR, Tin, nw, etotal);

        for (int it = 0; it < 3; it++) {
            // adjacency: mean -> NA/NB (bf16 split) -> sigmoid MFMA
            mean_nab_k<<<dim3(38), dim3(256), 0, stream>>>(
                CUR, Wa, Wb, NAH, NAL, NBH, NBL, BW);
            adjmm_k<<<dim3(5, 5), dim3(256), 0, stream>>>(
                NAH, NAL, NBH, NBL, ADJ);

            // QKV projection (split-bf16 MFMA, XCD-swizzled)
            qkv_mfma_k<<<dim3(BW * 15), dim3(256), 0, stream>>>(
                CUR, WQH, WQL, bqkv, QH, QL, KH, KL, VTH, VTL);

            // fused attention (R13 config)
            attn_k<<<dim3(BW * 10), dim3(256), 0, stream>>>(
                QH, QL, KH, KL, VTH, VTL, ADJ, OB, inv_sqrt_att);

            // cur = O @ Wlin + blin (split-bf16 MFMA)
            wlin_k<<<dim3((Mtot + 127) / 128), dim3(256), 0, stream>>>(
                OB, WTH, WTL, blin, CUR, Mtot);

            // running max of middle window
            long mtot = (long)BW * Nc * Cc;
            cand_update_k<<<dim3((unsigned)((mtot + 255) / 256)), dim3(256), 0, stream>>>(
                CUR, CAND, 0, mtot, it == 0 ? 1 : 0);
        }
    }
    output_k<<<dim3(Bc * Nc), dim3(128), 0, stream>>>(CAND, Wo, bo, out);
}